// Round 4
// baseline (31914.761 us; speedup 1.0000x reference)
//
#include <hip/hip_runtime.h>
#include <hip/hip_fp16.h>

// Problem dims (fixed by the reference)
#define T_DIM 4096
#define I_DIM 512
#define H_DIM 1024
#define O_DIM 256

// Recurrence kernel geometry
#define NWG 64        // persistent workgroups
#define RTHREADS 256  // 4 waves; 64 rows/WG x 4 k-lanes/row

typedef _Float16 half2v __attribute__((ext_vector_type(2)));

__device__ __forceinline__ float sigmoid_fast(float x) {
    return 1.f / (1.f + __expf(-x));
}
__device__ __forceinline__ float tanh_fast(float x) {
    float ax = fabsf(x);
    float e  = __expf(-2.f * ax);
    float t  = (1.f - e) / (1.f + e);
    return copysignf(t, x);
}

// fp16 dot2 with fp32 accumulate; uses v_dot2_f32_f16 when available.
__device__ __forceinline__ float dot2u(unsigned int a, unsigned int b, float c) {
#if __has_builtin(__builtin_amdgcn_fdot2)
    return __builtin_amdgcn_fdot2(__builtin_bit_cast(half2v, a),
                                  __builtin_bit_cast(half2v, b), c, false);
#else
    half2v ha = __builtin_bit_cast(half2v, a);
    half2v hb = __builtin_bit_cast(half2v, b);
    return c + (float)ha.x * (float)hb.x + (float)ha.y * (float)hb.y;
#endif
}

// ---------------------------------------------------------------------------
// Kernel A1: pack the 4 Wx matrices into one [4096][512] row-major buffer and
// the 4 biases into bpack[4096]. Row R = g*1024 + h, gate order f,i,c,o.
// ---------------------------------------------------------------------------
__global__ void pack_wx_bias(const float* __restrict__ wxf, const float* __restrict__ wxi,
                             const float* __restrict__ wxc, const float* __restrict__ wxo,
                             const float* __restrict__ bf,  const float* __restrict__ bi,
                             const float* __restrict__ bc,  const float* __restrict__ bo,
                             float* __restrict__ wxp, float* __restrict__ bpack) {
    int idx = blockIdx.x * 256 + threadIdx.x;
    const int total = 4 * H_DIM * I_DIM;
    if (idx < total) {
        int R = idx >> 9;          // / I_DIM
        int k = idx & (I_DIM - 1);
        int g = R >> 10;
        int h = R & (H_DIM - 1);
        const float* w = (g == 0) ? wxf : (g == 1) ? wxi : (g == 2) ? wxc : wxo;
        wxp[idx] = w[h * I_DIM + k];
    }
    if (idx < 4 * H_DIM) {
        int g = idx >> 10, h = idx & (H_DIM - 1);
        const float* b = (g == 0) ? bf : (g == 1) ? bi : (g == 2) ? bc : bo;
        bpack[idx] = b[h];
    }
}

// ---------------------------------------------------------------------------
// Kernel A2: convert Wh_* to fp16 packed for the LDS-resident layout.
// Thread (wg,tid) owns gate g=(tid>>6)&3, jj=(tid>>2)&15 (j=wg*16+jj),
// k-slice q=tid&3, elements e=0..255 (k=q*256+e). Element e of thread tid
// is stored at uint4 index  wg*8192 + (e/8)*256 + tid, half slot e%8.
// This makes both the global->LDS copy (lane-linear uint4) and the per-step
// ds_read_b128 (lane stride 16B) perfectly coalesced / conflict-free.
// ---------------------------------------------------------------------------
__global__ void pack_wh_f16(const float* __restrict__ whf, const float* __restrict__ whi,
                            const float* __restrict__ whc, const float* __restrict__ who,
                            __half* __restrict__ wh16) {
    int d = blockIdx.x * 256 + threadIdx.x;   // half index
    if (d >= 4 * H_DIM * H_DIM) return;
    int u4  = d >> 3;
    int h8  = d & 7;
    int wg  = u4 >> 13;        // / 8192
    int rem = u4 & 8191;
    int i   = rem >> 8;        // uint4 chunk 0..31
    int tid = rem & 255;
    int e = i * 8 + h8;
    int g = (tid >> 6) & 3;
    int jj = (tid >> 2) & 15;
    int q = tid & 3;
    int j = wg * 16 + jj;
    int k = q * 256 + e;
    const float* w = (g == 0) ? whf : (g == 1) ? whi : (g == 2) ? whc : who;
    wh16[d] = __float2half(w[j * H_DIM + k]);
}

// ---------------------------------------------------------------------------
// Shared fp32 GEMM: C[M][N] = A[M][K] * B[N][K]^T + bias[N]
// Tiles 64x64, BK=16, 256 threads, 4x4 accum per thread. All dims divide.
// ---------------------------------------------------------------------------
#define BM 64
#define BN 64
#define BK 16
__global__ __launch_bounds__(256) void gemm_bt(const float* __restrict__ A,
                                               const float* __restrict__ B,
                                               const float* __restrict__ bias,
                                               float* __restrict__ C,
                                               int M, int N, int K) {
    __shared__ float As[BK][BM + 4];
    __shared__ float Bs[BK][BN + 4];
    int tid = threadIdx.x;
    int m0 = blockIdx.y * BM, n0 = blockIdx.x * BN;
    int tx = tid & 15, ty = tid >> 4;
    float acc[4][4] = {};
    for (int k0 = 0; k0 < K; k0 += BK) {
#pragma unroll
        for (int l = 0; l < 4; ++l) {
            int idx = tid + l * 256;     // 0..1023
            int m = idx >> 4, k = idx & 15;
            As[k][m] = A[(long)(m0 + m) * K + k0 + k];
            Bs[k][m] = B[(long)(n0 + m) * K + k0 + k];
        }
        __syncthreads();
#pragma unroll
        for (int kk = 0; kk < BK; ++kk) {
            float ra[4], rb[4];
#pragma unroll
            for (int i = 0; i < 4; ++i) ra[i] = As[kk][ty * 4 + i];
#pragma unroll
            for (int j = 0; j < 4; ++j) rb[j] = Bs[kk][tx * 4 + j];
#pragma unroll
            for (int i = 0; i < 4; ++i)
#pragma unroll
                for (int j = 0; j < 4; ++j) acc[i][j] += ra[i] * rb[j];
        }
        __syncthreads();
    }
#pragma unroll
    for (int i = 0; i < 4; ++i) {
        int m = m0 + ty * 4 + i;
#pragma unroll
        for (int j = 0; j < 4; ++j) {
            int n = n0 + tx * 4 + j;
            C[(long)m * N + n] = acc[i][j] + bias[n];
        }
    }
}

// ---------------------------------------------------------------------------
// Kernel C: persistent recurrence, weights LDS-RESIDENT (128 KB/WG).
// LDS is immune to the per-step agent-scope buffer_inv that the acquire
// fence emits (which was re-flushing L2-cached weights every step in r2/r3).
// Per step: 32x ds_read_b128 (weights) + 32x uint4 h loads + 128 v_dot2,
// shfl reduce over 4 k-lanes, gates by 16 threads, h broadcast via global
// double buffer, padded per-WG timestamp flags (release store + wave-0
// parallel ballot poll).
// ---------------------------------------------------------------------------
__global__ __launch_bounds__(RTHREADS, 1) void lstm_recurrence(
    const float* __restrict__ gx,          // [T][4*H]
    const uint4* __restrict__ wh16,        // packed, uint4 units
    __half* __restrict__ hbuf,             // [2][H]
    float* __restrict__ hs,                // [T][H]
    unsigned int* __restrict__ flags) {    // [NWG][32] padded timestamps
    extern __shared__ uint4 wlds[];        // 8192 uint4 = 128 KB
    const int wg = blockIdx.x, tid = threadIdx.x;
    const int g = (tid >> 6) & 3;
    const int jj = (tid >> 2) & 15;
    const int q = tid & 3;
    const int j = wg * 16 + jj;
    const int R = g * H_DIM + j;

    __shared__ float lds_gate[4][16];
    __shared__ float lds_c[16];
    if (tid < 16) lds_c[tid] = 0.f;

    // One-time: stage this WG's weight slice into LDS (coalesced).
    const uint4* wsrc = wh16 + (long)wg * 8192;
#pragma unroll
    for (int i = 0; i < 32; ++i) wlds[i * 256 + tid] = wsrc[i * 256 + tid];

    float gx_next = gx[R];  // t = 0 pre-activation for this row
    __syncthreads();

    for (int t = 0; t < T_DIM; ++t) {
        float gxv = gx_next;
        if (t + 1 < T_DIM) gx_next = gx[(long)(t + 1) * (4 * H_DIM) + R];  // prefetch

        // h chunk for this k-slice: halves [q*256, q*256+256) of hbuf[t&1]
        const uint4* hb = (const uint4*)(hbuf + (t & 1) * H_DIM) + q * 32;
        float a0 = 0.f, a1 = 0.f, a2 = 0.f, a3 = 0.f;
#pragma unroll
        for (int i = 0; i < 32; ++i) {
            uint4 hv = hb[i];
            uint4 wv = wlds[i * 256 + tid];
            a0 = dot2u(hv.x, wv.x, a0);
            a1 = dot2u(hv.y, wv.y, a1);
            a2 = dot2u(hv.z, wv.z, a2);
            a3 = dot2u(hv.w, wv.w, a3);
        }
        float s = (a0 + a1) + (a2 + a3);
        s += __shfl_xor(s, 1);
        s += __shfl_xor(s, 2);
        if (q == 0) lds_gate[g][jj] = s + gxv;
        __syncthreads();

        if (tid < 16) {
            float gf = lds_gate[0][tid], gi = lds_gate[1][tid];
            float gc = lds_gate[2][tid], go = lds_gate[3][tid];
            float c  = lds_c[tid];
            float f  = sigmoid_fast(gf);
            float ii = sigmoid_fast(gi);
            float cd = tanh_fast(gc);
            float o  = sigmoid_fast(go);
            float cn = f * c + ii * cd;
            float hn = o * cn;  // reference omits tanh(c_t)
            lds_c[tid] = cn;
            int jg = wg * 16 + tid;
            hbuf[((t + 1) & 1) * H_DIM + jg] = __float2half(hn);
            hs[(long)t * H_DIM + jg] = hn;
        }
        // Release-store arrival timestamp (same wave as the h stores, so the
        // emitted vmcnt(0) covers them).
        if (tid == 0) {
            __hip_atomic_store(flags + wg * 32, (unsigned int)(t + 1),
                               __ATOMIC_RELEASE, __HIP_MEMORY_SCOPE_AGENT);
        }
        // Wave 0 polls all 64 flags in parallel: lane L watches flag L.
        if (tid < 64) {
            const unsigned int target = (unsigned int)(t + 1);
            const unsigned int* myflag = flags + tid * 32;
            for (;;) {
                unsigned int v = __hip_atomic_load(myflag, __ATOMIC_RELAXED,
                                                   __HIP_MEMORY_SCOPE_AGENT);
                unsigned long long ready = __ballot(v >= target);
                if (ready == ~0ull) break;
            }
        }
        __syncthreads();
        __builtin_amdgcn_fence(__ATOMIC_ACQUIRE, "agent");
    }
}

// ---------------------------------------------------------------------------
extern "C" void kernel_launch(void* const* d_in, const int* in_sizes, int n_in,
                              void* d_out, int out_size, void* d_ws, size_t ws_size,
                              hipStream_t stream) {
    (void)in_sizes; (void)n_in; (void)out_size; (void)ws_size;
    const float* x    = (const float*)d_in[0];
    const float* wxf  = (const float*)d_in[1];
    const float* whf  = (const float*)d_in[2];
    const float* bf   = (const float*)d_in[3];
    const float* wxi  = (const float*)d_in[4];
    const float* whi  = (const float*)d_in[5];
    const float* bi   = (const float*)d_in[6];
    const float* wxc  = (const float*)d_in[7];
    const float* whc  = (const float*)d_in[8];
    const float* bc   = (const float*)d_in[9];
    const float* wxo  = (const float*)d_in[10];
    const float* who  = (const float*)d_in[11];
    const float* bo   = (const float*)d_in[12];
    const float* wy   = (const float*)d_in[13];
    const float* by   = (const float*)d_in[14];
    float* y_out = (float*)d_out;

    // Workspace layout (bytes)
    char* base = (char*)d_ws;
    float*  gx    = (float*)(base + 0);                       // 64 MB: [T][4H]
    float*  wxp   = (float*)(base + (size_t)64 * 1024 * 1024);// 8 MB
    float*  bpack = (float*)(base + (size_t)72 * 1024 * 1024);// 16 KB
    __half* wh16  = (__half*)(base + (size_t)72 * 1024 * 1024 + 16384); // 8 MB
    float*  hs    = (float*)(base + (size_t)80 * 1024 * 1024 + 16384);  // 16 MB
    __half* hbuf  = (__half*)(base + (size_t)96 * 1024 * 1024 + 16384); // 4 KB
    unsigned int* flags = (unsigned int*)(base + (size_t)96 * 1024 * 1024 + 16384 + 4096); // 8 KB

    // Allow 128 KB dynamic LDS for the recurrence kernel (host-side call,
    // not a stream op — safe under graph capture; idempotent).
    hipFuncSetAttribute((const void*)lstm_recurrence,
                        hipFuncAttributeMaxDynamicSharedMemorySize, 128 * 1024);

    // Zero h0 double-buffer + flag timestamps (ws is poisoned 0xAA each run).
    hipMemsetAsync(hbuf, 0, 4096 + 8192, stream);

    pack_wx_bias<<<(4 * H_DIM * I_DIM + 255) / 256, 256, 0, stream>>>(
        wxf, wxi, wxc, wxo, bf, bi, bc, bo, wxp, bpack);
    pack_wh_f16<<<(4 * H_DIM * H_DIM + 255) / 256, 256, 0, stream>>>(
        whf, whi, whc, who, wh16);

    // gx = x @ WxPack^T + bPack : [4096, 4096]
    gemm_bt<<<dim3((4 * H_DIM) / BN, T_DIM / BM), 256, 0, stream>>>(
        x, wxp, bpack, gx, T_DIM, 4 * H_DIM, I_DIM);

    lstm_recurrence<<<NWG, RTHREADS, 128 * 1024, stream>>>(
        gx, (const uint4*)wh16, hbuf, hs, flags);

    // y = hs @ Wy^T + by : [4096, 256]
    gemm_bt<<<dim3(O_DIM / BN, T_DIM / BM), 256, 0, stream>>>(
        hs, wy, by, y_out, T_DIM, O_DIM, H_DIM);
}

// Round 5
// 10710.889 us; speedup vs baseline: 2.9797x; 2.9797x over previous
//
#include <hip/hip_runtime.h>
#include <hip/hip_fp16.h>

// Problem dims (fixed by the reference)
#define T_DIM 4096
#define I_DIM 512
#define H_DIM 1024
#define O_DIM 256

// Recurrence kernel geometry
#define NWG 64        // persistent workgroups
#define RTHREADS 256  // 4 waves; 64 rows/WG x 4 k-lanes/row

typedef _Float16 half2v __attribute__((ext_vector_type(2)));
typedef unsigned int u32x4 __attribute__((ext_vector_type(4)));

__device__ __forceinline__ float sigmoid_fast(float x) {
    return 1.f / (1.f + __expf(-x));
}
__device__ __forceinline__ float tanh_fast(float x) {
    float ax = fabsf(x);
    float e  = __expf(-2.f * ax);
    float t  = (1.f - e) / (1.f + e);
    return copysignf(t, x);
}

// fp16 dot2 with fp32 accumulate; uses v_dot2_f32_f16 when available.
__device__ __forceinline__ float dot2u(unsigned int a, unsigned int b, float c) {
#if __has_builtin(__builtin_amdgcn_fdot2)
    return __builtin_amdgcn_fdot2(__builtin_bit_cast(half2v, a),
                                  __builtin_bit_cast(half2v, b), c, false);
#else
    half2v ha = __builtin_bit_cast(half2v, a);
    half2v hb = __builtin_bit_cast(half2v, b);
    return c + (float)ha.x * (float)hb.x + (float)ha.y * (float)hb.y;
#endif
}

// L3-coherent (L1/L2-bypass) 16B load/store — what agent-scope atomics lower
// to on gfx950. Single-instruction 16B payload carries stamp+data together.
__device__ __forceinline__ u32x4 load_l3(const u32x4* p) {
    u32x4 r;
    asm volatile("global_load_dwordx4 %0, %1, off sc0 sc1\n\t"
                 "s_waitcnt vmcnt(0)"
                 : "=v"(r) : "v"(p) : "memory");
    return r;
}
__device__ __forceinline__ void store_l3(u32x4* p, u32x4 v) {
    asm volatile("global_store_dwordx4 %0, %1, off sc0 sc1"
                 :: "v"(p), "v"(v) : "memory");
}

// ---------------------------------------------------------------------------
// Kernel A1: pack the 4 Wx matrices into one [4096][512] row-major buffer and
// the 4 biases into bpack[4096]. Row R = g*1024 + h, gate order f,i,c,o.
// ---------------------------------------------------------------------------
__global__ void pack_wx_bias(const float* __restrict__ wxf, const float* __restrict__ wxi,
                             const float* __restrict__ wxc, const float* __restrict__ wxo,
                             const float* __restrict__ bf,  const float* __restrict__ bi,
                             const float* __restrict__ bc,  const float* __restrict__ bo,
                             float* __restrict__ wxp, float* __restrict__ bpack) {
    int idx = blockIdx.x * 256 + threadIdx.x;
    const int total = 4 * H_DIM * I_DIM;
    if (idx < total) {
        int R = idx >> 9;          // / I_DIM
        int k = idx & (I_DIM - 1);
        int g = R >> 10;
        int h = R & (H_DIM - 1);
        const float* w = (g == 0) ? wxf : (g == 1) ? wxi : (g == 2) ? wxc : wxo;
        wxp[idx] = w[h * I_DIM + k];
    }
    if (idx < 4 * H_DIM) {
        int g = idx >> 10, h = idx & (H_DIM - 1);
        const float* b = (g == 0) ? bf : (g == 1) ? bi : (g == 2) ? bc : bo;
        bpack[idx] = b[h];
    }
}

// ---------------------------------------------------------------------------
// Kernel A2: convert Wh_* to fp16 packed for the LDS-resident layout.
// Thread (wg,tid) owns gate g=(tid>>6)&3, jj=(tid>>2)&15 (j=wg*16+jj),
// k-slice q=tid&3, elements e=0..255 (k=q*256+e). Element e of thread tid
// is stored at uint4 index  wg*8192 + (e/8)*256 + tid, half slot e%8.
// ---------------------------------------------------------------------------
__global__ void pack_wh_f16(const float* __restrict__ whf, const float* __restrict__ whi,
                            const float* __restrict__ whc, const float* __restrict__ who,
                            __half* __restrict__ wh16) {
    int d = blockIdx.x * 256 + threadIdx.x;   // half index
    if (d >= 4 * H_DIM * H_DIM) return;
    int u4  = d >> 3;
    int h8  = d & 7;
    int wg  = u4 >> 13;        // / 8192
    int rem = u4 & 8191;
    int i   = rem >> 8;        // uint4 chunk 0..31
    int tid = rem & 255;
    int e = i * 8 + h8;
    int g = (tid >> 6) & 3;
    int jj = (tid >> 2) & 15;
    int q = tid & 3;
    int j = wg * 16 + jj;
    int k = q * 256 + e;
    const float* w = (g == 0) ? whf : (g == 1) ? whi : (g == 2) ? whc : who;
    wh16[d] = __float2half(w[j * H_DIM + k]);
}

// ---------------------------------------------------------------------------
// Shared fp32 GEMM: C[M][N] = A[M][K] * B[N][K]^T + bias[N]
// Tiles 64x64, BK=16, 256 threads, 4x4 accum per thread. All dims divide.
// ---------------------------------------------------------------------------
#define BM 64
#define BN 64
#define BK 16
__global__ __launch_bounds__(256) void gemm_bt(const float* __restrict__ A,
                                               const float* __restrict__ B,
                                               const float* __restrict__ bias,
                                               float* __restrict__ C,
                                               int M, int N, int K) {
    __shared__ float As[BK][BM + 4];
    __shared__ float Bs[BK][BN + 4];
    int tid = threadIdx.x;
    int m0 = blockIdx.y * BM, n0 = blockIdx.x * BN;
    int tx = tid & 15, ty = tid >> 4;
    float acc[4][4] = {};
    for (int k0 = 0; k0 < K; k0 += BK) {
#pragma unroll
        for (int l = 0; l < 4; ++l) {
            int idx = tid + l * 256;     // 0..1023
            int m = idx >> 4, k = idx & 15;
            As[k][m] = A[(long)(m0 + m) * K + k0 + k];
            Bs[k][m] = B[(long)(n0 + m) * K + k0 + k];
        }
        __syncthreads();
#pragma unroll
        for (int kk = 0; kk < BK; ++kk) {
            float ra[4], rb[4];
#pragma unroll
            for (int i = 0; i < 4; ++i) ra[i] = As[kk][ty * 4 + i];
#pragma unroll
            for (int j = 0; j < 4; ++j) rb[j] = Bs[kk][tx * 4 + j];
#pragma unroll
            for (int i = 0; i < 4; ++i)
#pragma unroll
                for (int j = 0; j < 4; ++j) acc[i][j] += ra[i] * rb[j];
        }
        __syncthreads();
    }
#pragma unroll
    for (int i = 0; i < 4; ++i) {
        int m = m0 + ty * 4 + i;
#pragma unroll
        for (int j = 0; j < 4; ++j) {
            int n = n0 + tx * 4 + j;
            C[(long)m * N + n] = acc[i][j] + bias[n];
        }
    }
}

// ---------------------------------------------------------------------------
// Kernel C: persistent recurrence, weights LDS-resident, h handoff fused
// into the sync lines (stamp+data in one 16B chunk, double-buffered by
// parity, double-stamp tear guard). ONE L3 round trip per step, no fences,
// no buffer_inv. bc layout: [parity][64 lines][128B]; line = 4 chunks of
// {stamp, h2, h2, stamp}; line L chunk c carries h[L*16+4c .. L*16+4c+3].
// ---------------------------------------------------------------------------
__global__ __launch_bounds__(RTHREADS, 1) void lstm_recurrence(
    const float* __restrict__ gx,          // [T][4*H]
    const uint4* __restrict__ wh16,        // packed weights, uint4 units
    u32x4* __restrict__ bc,                // [2][64][8] u32x4 (16 KB)
    float* __restrict__ hs) {              // [T][H]
    extern __shared__ uint4 wlds[];        // 8192 uint4 = 128 KB
    const int wg = blockIdx.x, tid = threadIdx.x;
    const int g = (tid >> 6) & 3;
    const int jj = (tid >> 2) & 15;
    const int q = tid & 3;
    const int j = wg * 16 + jj;
    const int R = g * H_DIM + j;

    __shared__ float lds_gate[4][16];
    __shared__ float lds_c[16];
    __shared__ unsigned short lds_pub[16];
    __shared__ unsigned int __attribute__((aligned(16))) lds_h32[512]; // h_t as 512 h2
    if (tid < 16) lds_c[tid] = 0.f;

    // One-time: stage this WG's weight slice into LDS (coalesced).
    const uint4* wsrc = wh16 + (long)wg * 8192;
#pragma unroll
    for (int i = 0; i < 32; ++i) wlds[i * 256 + tid] = wsrc[i * 256 + tid];

    // Poll assignment: thread watches line L=tid&63, chunk c=tid>>6.
    const int pL = tid & 63, pc = tid >> 6;

    float gx_next = gx[R];  // t = 0 pre-activation for this row
    __syncthreads();

    for (int t = 0; t < T_DIM; ++t) {
        float gxv = gx_next;
        if (t + 1 < T_DIM) gx_next = gx[(long)(t + 1) * (4 * H_DIM) + R];  // prefetch

        // ---- Poll: one L3 load returns stamp AND h payload together.
        {
            const unsigned int target = (unsigned int)t;
            const u32x4* addr = bc + (size_t)(t & 1) * 512 + pL * 8 + pc;
            u32x4 v;
            do {
                v = load_l3(addr);
            } while (v.x != target || v.w != target);
            lds_h32[pL * 8 + pc * 2]     = v.y;
            lds_h32[pL * 8 + pc * 2 + 1] = v.z;
        }
        __syncthreads();

        // ---- Matvec: weights from LDS, h from LDS.
        const uint4* hlds = (const uint4*)lds_h32 + q * 32;
        float a0 = 0.f, a1 = 0.f, a2 = 0.f, a3 = 0.f;
#pragma unroll
        for (int i = 0; i < 32; ++i) {
            uint4 hv = hlds[i];
            uint4 wv = wlds[i * 256 + tid];
            a0 = dot2u(hv.x, wv.x, a0);
            a1 = dot2u(hv.y, wv.y, a1);
            a2 = dot2u(hv.z, wv.z, a2);
            a3 = dot2u(hv.w, wv.w, a3);
        }
        float s = (a0 + a1) + (a2 + a3);
        s += __shfl_xor(s, 1);
        s += __shfl_xor(s, 2);
        if (q == 0) lds_gate[g][jj] = s + gxv;
        __syncthreads();

        // ---- Gates + publish (wave 0 only; other waves run ahead to poll).
        float hn = 0.f;
        if (tid < 16) {
            float gf = lds_gate[0][tid], gi = lds_gate[1][tid];
            float gc = lds_gate[2][tid], go = lds_gate[3][tid];
            float c  = lds_c[tid];
            float f  = sigmoid_fast(gf);
            float ii = sigmoid_fast(gi);
            float cd = tanh_fast(gc);
            float o  = sigmoid_fast(go);
            float cn = f * c + ii * cd;
            hn = o * cn;  // reference omits tanh(c_t)
            lds_c[tid] = cn;
            lds_pub[tid] = __half_as_ushort(__float2half(hn));
        }
        // Same wave (lockstep): LDS write->read needs no barrier.
        if (tid < 4) {
            unsigned int stamp = (unsigned int)(t + 1);
            unsigned int u0 = (unsigned int)lds_pub[4 * tid] |
                              ((unsigned int)lds_pub[4 * tid + 1] << 16);
            unsigned int u1 = (unsigned int)lds_pub[4 * tid + 2] |
                              ((unsigned int)lds_pub[4 * tid + 3] << 16);
            u32x4 out; out.x = stamp; out.y = u0; out.z = u1; out.w = stamp;
            store_l3(bc + (size_t)((t + 1) & 1) * 512 + wg * 8 + tid, out);
        }
        if (tid < 16) {
            hs[(long)t * H_DIM + wg * 16 + tid] = hn;  // off critical path
        }
    }
}

// ---------------------------------------------------------------------------
extern "C" void kernel_launch(void* const* d_in, const int* in_sizes, int n_in,
                              void* d_out, int out_size, void* d_ws, size_t ws_size,
                              hipStream_t stream) {
    (void)in_sizes; (void)n_in; (void)out_size; (void)ws_size;
    const float* x    = (const float*)d_in[0];
    const float* wxf  = (const float*)d_in[1];
    const float* whf  = (const float*)d_in[2];
    const float* bf   = (const float*)d_in[3];
    const float* wxi  = (const float*)d_in[4];
    const float* whi  = (const float*)d_in[5];
    const float* bi   = (const float*)d_in[6];
    const float* wxc  = (const float*)d_in[7];
    const float* whc  = (const float*)d_in[8];
    const float* bc_  = (const float*)d_in[9];
    const float* wxo  = (const float*)d_in[10];
    const float* who  = (const float*)d_in[11];
    const float* bo   = (const float*)d_in[12];
    const float* wy   = (const float*)d_in[13];
    const float* by   = (const float*)d_in[14];
    float* y_out = (float*)d_out;

    // Workspace layout (bytes)
    char* base = (char*)d_ws;
    float*  gx    = (float*)(base + 0);                       // 64 MB: [T][4H]
    float*  wxp   = (float*)(base + (size_t)64 * 1024 * 1024);// 8 MB
    float*  bpack = (float*)(base + (size_t)72 * 1024 * 1024);// 16 KB
    __half* wh16  = (__half*)(base + (size_t)72 * 1024 * 1024 + 16384); // 8 MB
    float*  hs    = (float*)(base + (size_t)80 * 1024 * 1024 + 16384);  // 16 MB
    u32x4*  bcast = (u32x4*)(base + (size_t)96 * 1024 * 1024 + 16384);  // 16 KB

    // Allow 128 KB dynamic LDS for the recurrence kernel (host-side, capture-safe).
    hipFuncSetAttribute((const void*)lstm_recurrence,
                        hipFuncAttributeMaxDynamicSharedMemorySize, 128 * 1024);

    // Zero the broadcast lines: stamp 0 + h0 = 0 is exactly step-0's input.
    hipMemsetAsync(bcast, 0, 16384, stream);

    pack_wx_bias<<<(4 * H_DIM * I_DIM + 255) / 256, 256, 0, stream>>>(
        wxf, wxi, wxc, wxo, bf, bi, bc_, bo, wxp, bpack);
    pack_wh_f16<<<(4 * H_DIM * H_DIM + 255) / 256, 256, 0, stream>>>(
        whf, whi, whc, who, wh16);

    // gx = x @ WxPack^T + bPack : [4096, 4096]
    gemm_bt<<<dim3((4 * H_DIM) / BN, T_DIM / BM), 256, 0, stream>>>(
        x, wxp, bpack, gx, T_DIM, 4 * H_DIM, I_DIM);

    lstm_recurrence<<<NWG, RTHREADS, 128 * 1024, stream>>>(
        gx, (const uint4*)wh16, bcast, hs);

    // y = hs @ Wy^T + by : [4096, 256]
    gemm_bt<<<dim3(O_DIM / BN, T_DIM / BM), 256, 0, stream>>>(
        hs, wy, by, y_out, T_DIM, O_DIM, H_DIM);
}

// Round 6
// 9801.337 us; speedup vs baseline: 3.2562x; 1.0928x over previous
//
#include <hip/hip_runtime.h>
#include <hip/hip_fp16.h>

// Problem dims (fixed by the reference)
#define T_DIM 4096
#define I_DIM 512
#define H_DIM 1024
#define O_DIM 256

// Recurrence kernel geometry: 256 WGs (1 per CU), 256 threads.
// WG w owns rows (g, j=w*4+jj) for g=0..3, jj=0..3 (16 rows).
// Thread tid: g=tid>>6, jj=(tid>>4)&3, k-slice s=tid&15 (k = s*64+e, e=0..63).
#define NWG 256
#define RTHREADS 256

typedef _Float16 half2v __attribute__((ext_vector_type(2)));
typedef unsigned int u32x4 __attribute__((ext_vector_type(4)));

__device__ __forceinline__ float sigmoid_fast(float x) {
    return 1.f / (1.f + __expf(-x));
}
__device__ __forceinline__ float tanh_fast(float x) {
    float ax = fabsf(x);
    float e  = __expf(-2.f * ax);
    float t  = (1.f - e) / (1.f + e);
    return copysignf(t, x);
}

// fp16 dot2 with fp32 accumulate; uses v_dot2_f32_f16 when available.
__device__ __forceinline__ float dot2u(unsigned int a, unsigned int b, float c) {
#if __has_builtin(__builtin_amdgcn_fdot2)
    return __builtin_amdgcn_fdot2(__builtin_bit_cast(half2v, a),
                                  __builtin_bit_cast(half2v, b), c, false);
#else
    half2v ha = __builtin_bit_cast(half2v, a);
    half2v hb = __builtin_bit_cast(half2v, b);
    return c + (float)ha.x * (float)hb.x + (float)ha.y * (float)hb.y;
#endif
}

// L3-coherent (L1/L2-bypass) 16B load/store.
__device__ __forceinline__ u32x4 load_l3(const u32x4* p) {
    u32x4 r;
    asm volatile("global_load_dwordx4 %0, %1, off sc0 sc1\n\t"
                 "s_waitcnt vmcnt(0)"
                 : "=v"(r) : "v"(p) : "memory");
    return r;
}
__device__ __forceinline__ void store_l3(u32x4* p, u32x4 v) {
    asm volatile("global_store_dwordx4 %0, %1, off sc0 sc1"
                 :: "v"(p), "v"(v) : "memory");
}

// ---------------------------------------------------------------------------
// Kernel A1: pack the 4 Wx matrices into one [4096][512] row-major buffer and
// the 4 biases into bpack[4096]. Row R = g*1024 + h, gate order f,i,c,o.
// ---------------------------------------------------------------------------
__global__ void pack_wx_bias(const float* __restrict__ wxf, const float* __restrict__ wxi,
                             const float* __restrict__ wxc, const float* __restrict__ wxo,
                             const float* __restrict__ bf,  const float* __restrict__ bi,
                             const float* __restrict__ bc,  const float* __restrict__ bo,
                             float* __restrict__ wxp, float* __restrict__ bpack) {
    int idx = blockIdx.x * 256 + threadIdx.x;
    const int total = 4 * H_DIM * I_DIM;
    if (idx < total) {
        int R = idx >> 9;          // / I_DIM
        int k = idx & (I_DIM - 1);
        int g = R >> 10;
        int h = R & (H_DIM - 1);
        const float* w = (g == 0) ? wxf : (g == 1) ? wxi : (g == 2) ? wxc : wxo;
        wxp[idx] = w[h * I_DIM + k];
    }
    if (idx < 4 * H_DIM) {
        int g = idx >> 10, h = idx & (H_DIM - 1);
        const float* b = (g == 0) ? bf : (g == 1) ? bi : (g == 2) ? bc : bo;
        bpack[idx] = b[h];
    }
}

// ---------------------------------------------------------------------------
// Kernel A2: convert Wh_* to fp16 packed for the 256-WG LDS layout.
// uint4 index = w*2048 + i*256 + tid  (i = 0..7), half slot e%8, e = i*8+h8.
// Thread (w,tid): g=tid>>6, jj=(tid>>4)&3, s=tid&15; j=w*4+jj; k=s*64+e.
// ---------------------------------------------------------------------------
__global__ void pack_wh_f16(const float* __restrict__ whf, const float* __restrict__ whi,
                            const float* __restrict__ whc, const float* __restrict__ who,
                            __half* __restrict__ wh16) {
    int d = blockIdx.x * 256 + threadIdx.x;   // half index, total 4M
    if (d >= 4 * H_DIM * H_DIM) return;
    int u4  = d >> 3;
    int h8  = d & 7;
    int w   = u4 >> 11;        // / 2048
    int rem = u4 & 2047;
    int i   = rem >> 8;        // uint4 chunk 0..7
    int tid = rem & 255;
    int e  = i * 8 + h8;
    int g  = tid >> 6;
    int jj = (tid >> 4) & 3;
    int s  = tid & 15;
    int j  = w * 4 + jj;
    int k  = s * 64 + e;
    const float* wsrc = (g == 0) ? whf : (g == 1) ? whi : (g == 2) ? whc : who;
    wh16[d] = __float2half(wsrc[j * H_DIM + k]);
}

// ---------------------------------------------------------------------------
// Shared fp32 GEMM: C[M][N] = A[M][K] * B[N][K]^T + bias[N]
// Tiles 64x64, BK=16, 256 threads, 4x4 accum per thread. All dims divide.
// ---------------------------------------------------------------------------
#define BM 64
#define BN 64
#define BK 16
__global__ __launch_bounds__(256) void gemm_bt(const float* __restrict__ A,
                                               const float* __restrict__ B,
                                               const float* __restrict__ bias,
                                               float* __restrict__ C,
                                               int M, int N, int K) {
    __shared__ float As[BK][BM + 4];
    __shared__ float Bs[BK][BN + 4];
    int tid = threadIdx.x;
    int m0 = blockIdx.y * BM, n0 = blockIdx.x * BN;
    int tx = tid & 15, ty = tid >> 4;
    float acc[4][4] = {};
    for (int k0 = 0; k0 < K; k0 += BK) {
#pragma unroll
        for (int l = 0; l < 4; ++l) {
            int idx = tid + l * 256;     // 0..1023
            int m = idx >> 4, k = idx & 15;
            As[k][m] = A[(long)(m0 + m) * K + k0 + k];
            Bs[k][m] = B[(long)(n0 + m) * K + k0 + k];
        }
        __syncthreads();
#pragma unroll
        for (int kk = 0; kk < BK; ++kk) {
            float ra[4], rb[4];
#pragma unroll
            for (int i = 0; i < 4; ++i) ra[i] = As[kk][ty * 4 + i];
#pragma unroll
            for (int j = 0; j < 4; ++j) rb[j] = Bs[kk][tx * 4 + j];
#pragma unroll
            for (int i = 0; i < 4; ++i)
#pragma unroll
                for (int j = 0; j < 4; ++j) acc[i][j] += ra[i] * rb[j];
        }
        __syncthreads();
    }
#pragma unroll
    for (int i = 0; i < 4; ++i) {
        int m = m0 + ty * 4 + i;
#pragma unroll
        for (int j = 0; j < 4; ++j) {
            int n = n0 + tx * 4 + j;
            C[(long)m * N + n] = acc[i][j] + bias[n];
        }
    }
}

// ---------------------------------------------------------------------------
// Kernel C: persistent recurrence, 256 WGs x 256 threads (1 WG/CU).
// 16 rows/WG -> 32 KB LDS weights (static). h handoff fused into sync chunks:
// WG w publishes ONE u32x4 {stamp, h0h1, h2h3, stamp} per step (parity
// double-buffer). Thread tid polls publisher-WG tid's chunk; payload goes
// into a PADDED LDS h buffer (uint4 idx s*9+i -> banks 4(s+i)%32, worst
// 2-way = free) eliminating the r5 4-way conflicts. Matvec: 8 w-reads +
// 8 h-reads + 32 dot2/thread; reduce = 4x shfl_xor over 16 lanes.
// ---------------------------------------------------------------------------
__global__ __launch_bounds__(RTHREADS, 1) void lstm_recurrence(
    const float* __restrict__ gx,          // [T][4*H]
    const uint4* __restrict__ wpk,         // packed weights, uint4 units
    u32x4* __restrict__ bc,                // [2][256] u32x4 (8 KB)
    float* __restrict__ hs) {              // [T][H]
    __shared__ uint4 wlds[2048];                                  // 32 KB
    __shared__ unsigned int __attribute__((aligned(16))) hldsp[16 * 36]; // padded h
    __shared__ float lds_gate[4][4];
    __shared__ float lds_c[4];
    __shared__ unsigned short lds_pub[4];

    const int w = blockIdx.x, tid = threadIdx.x;
    const int g  = tid >> 6;
    const int jj = (tid >> 4) & 3;
    const int s  = tid & 15;
    const int R  = g * H_DIM + w * 4 + jj;

    if (tid < 4) lds_c[tid] = 0.f;

    // One-time: stage this WG's 32 KB weight slice into LDS (coalesced).
    const uint4* wsrc = wpk + (long)w * 2048;
#pragma unroll
    for (int i = 0; i < 8; ++i) wlds[i * 256 + tid] = wsrc[i * 256 + tid];

    float gx_next = (s == 0) ? gx[R] : 0.f;  // t=0 pre-activation (leader lanes)
    __syncthreads();

    for (int t = 0; t < T_DIM; ++t) {
        float gxv = gx_next;
        if (s == 0 && t + 1 < T_DIM)
            gx_next = gx[(long)(t + 1) * (4 * H_DIM) + R];  // prefetch

        // ---- Poll own chunk: stamp + 4 h values in one L3 load.
        {
            const unsigned int target = (unsigned int)t;
            const u32x4* addr = bc + (size_t)(t & 1) * NWG + tid;
            u32x4 v;
            do {
                v = load_l3(addr);
            } while (v.x != target || v.w != target);
            // h2 (u32) global idx U = tid*2 -> slice ss = U>>5, offset oo = U&31
            int ss = tid >> 4, oo = (tid * 2) & 31;
            hldsp[ss * 36 + oo]     = v.y;
            hldsp[ss * 36 + oo + 1] = v.z;
        }
        __syncthreads();

        // ---- Matvec: weights + padded h from LDS.
        float a0 = 0.f, a1 = 0.f, a2 = 0.f, a3 = 0.f;
#pragma unroll
        for (int i = 0; i < 8; ++i) {
            uint4 hv = ((const uint4*)hldsp)[s * 9 + i];
            uint4 wv = wlds[i * 256 + tid];
            a0 = dot2u(hv.x, wv.x, a0);
            a1 = dot2u(hv.y, wv.y, a1);
            a2 = dot2u(hv.z, wv.z, a2);
            a3 = dot2u(hv.w, wv.w, a3);
        }
        float sum = (a0 + a1) + (a2 + a3);
        sum += __shfl_xor(sum, 1);
        sum += __shfl_xor(sum, 2);
        sum += __shfl_xor(sum, 4);
        sum += __shfl_xor(sum, 8);
        if (s == 0) lds_gate[g][jj] = sum + gxv;
        __syncthreads();

        // ---- Gates + publish (lanes 0..3 of wave 0).
        float hn = 0.f;
        if (tid < 4) {
            float gf = lds_gate[0][tid], gi = lds_gate[1][tid];
            float gc = lds_gate[2][tid], go = lds_gate[3][tid];
            float c  = lds_c[tid];
            float f  = sigmoid_fast(gf);
            float ii = sigmoid_fast(gi);
            float cd = tanh_fast(gc);
            float o  = sigmoid_fast(go);
            float cn = f * c + ii * cd;
            hn = o * cn;  // reference omits tanh(c_t)
            lds_c[tid] = cn;
            lds_pub[tid] = __half_as_ushort(__float2half(hn));
        }
        // Same-wave LDS RAW (lockstep) — no barrier needed.
        if (tid == 0) {
            unsigned int stamp = (unsigned int)(t + 1);
            unsigned int u0 = (unsigned int)lds_pub[0] | ((unsigned int)lds_pub[1] << 16);
            unsigned int u1 = (unsigned int)lds_pub[2] | ((unsigned int)lds_pub[3] << 16);
            u32x4 out; out.x = stamp; out.y = u0; out.z = u1; out.w = stamp;
            store_l3(bc + (size_t)((t + 1) & 1) * NWG + w, out);
        }
        if (tid < 4) {
            hs[(long)t * H_DIM + w * 4 + tid] = hn;  // off critical path
        }
    }
}

// ---------------------------------------------------------------------------
extern "C" void kernel_launch(void* const* d_in, const int* in_sizes, int n_in,
                              void* d_out, int out_size, void* d_ws, size_t ws_size,
                              hipStream_t stream) {
    (void)in_sizes; (void)n_in; (void)out_size; (void)ws_size;
    const float* x    = (const float*)d_in[0];
    const float* wxf  = (const float*)d_in[1];
    const float* whf  = (const float*)d_in[2];
    const float* bf   = (const float*)d_in[3];
    const float* wxi  = (const float*)d_in[4];
    const float* whi  = (const float*)d_in[5];
    const float* bi   = (const float*)d_in[6];
    const float* wxc  = (const float*)d_in[7];
    const float* whc  = (const float*)d_in[8];
    const float* bc_  = (const float*)d_in[9];
    const float* wxo  = (const float*)d_in[10];
    const float* who  = (const float*)d_in[11];
    const float* bo   = (const float*)d_in[12];
    const float* wy   = (const float*)d_in[13];
    const float* by   = (const float*)d_in[14];
    float* y_out = (float*)d_out;

    // Workspace layout (bytes)
    char* base = (char*)d_ws;
    float*  gx    = (float*)(base + 0);                       // 64 MB: [T][4H]
    float*  wxp   = (float*)(base + (size_t)64 * 1024 * 1024);// 8 MB
    float*  bpack = (float*)(base + (size_t)72 * 1024 * 1024);// 16 KB
    __half* wh16  = (__half*)(base + (size_t)72 * 1024 * 1024 + 16384); // 8 MB
    float*  hs    = (float*)(base + (size_t)80 * 1024 * 1024 + 16384);  // 16 MB
    u32x4*  bcast = (u32x4*)(base + (size_t)96 * 1024 * 1024 + 16384);  // 8 KB

    // Zero the broadcast chunks: stamp 0 + h0 = 0 is exactly step-0's input.
    hipMemsetAsync(bcast, 0, 16384, stream);

    pack_wx_bias<<<(4 * H_DIM * I_DIM + 255) / 256, 256, 0, stream>>>(
        wxf, wxi, wxc, wxo, bf, bi, bc_, bo, wxp, bpack);
    pack_wh_f16<<<(4 * H_DIM * H_DIM + 255) / 256, 256, 0, stream>>>(
        whf, whi, whc, who, wh16);

    // gx = x @ WxPack^T + bPack : [4096, 4096]
    gemm_bt<<<dim3((4 * H_DIM) / BN, T_DIM / BM), 256, 0, stream>>>(
        x, wxp, bpack, gx, T_DIM, 4 * H_DIM, I_DIM);

    lstm_recurrence<<<NWG, RTHREADS, 0, stream>>>(
        gx, (const uint4*)wh16, bcast, hs);

    // y = hs @ Wy^T + by : [4096, 256]
    gemm_bt<<<dim3(O_DIM / BN, T_DIM / BM), 256, 0, stream>>>(
        hs, wy, by, y_out, T_DIM, O_DIM, H_DIM);
}